// Round 10
// baseline (280.758 us; speedup 1.0000x reference)
//
#include <hip/hip_runtime.h>
#include <hip/hip_fp16.h>
#include <math.h>

#define NN 50000
#define NE 800000
#define KDIM 128
#define NB 196            // dst buckets of 256 nodes: bucket = dst >> 8
#define CPAD 16           // pad global atomic counters to one per 64B line
#define STILE 4096        // edges per stage block

typedef _Float16 v8h __attribute__((ext_vector_type(8)));
typedef float v4f __attribute__((ext_vector_type(4)));

// ---------------- convert: feat -> fp16, W0/W1/W2 -> fp16 transposed [n][k] ----------------
#define FEAT_B4 6250   // NN*128/4 float4 chunks / 256 threads
__global__ __launch_bounds__(256) void convert_kernel(
    const float* __restrict__ feat, const float* __restrict__ W0,
    const float* __restrict__ W1, const float* __restrict__ W2,
    __half* __restrict__ feat_h, __half* __restrict__ W0T,
    __half* __restrict__ W1T, __half* __restrict__ W2T) {
  int b = blockIdx.x;
  int tid = threadIdx.x;
  if (b < FEAT_B4) {
    int i = b * 256 + tid;
    if (i < NN * 32) {
      float4 v = *(const float4*)&feat[(size_t)i * 4];
      union { __half2 h2[2]; int2 i2; } u;
      u.h2[0] = __floats2half2_rn(v.x, v.y);
      u.h2[1] = __floats2half2_rn(v.z, v.w);
      *(int2*)&feat_h[(size_t)i * 4] = u.i2;
    }
  } else {
    int gid = (b - FEAT_B4) * 256 + tid;
    if (gid < 16384) {
      int n = gid >> 7, k = gid & 127;
      W0T[gid] = __float2half(W0[k * 128 + n]);
    } else if (gid < 32768) {
      int g = gid - 16384; int n = g >> 7, k = g & 127;
      W1T[g] = __float2half(W1[k * 128 + n]);
    } else if (gid < 40960) {
      int g = gid - 32768; int n = g >> 7, k = g & 127;   // n<64, k<128
      W2T[g] = __float2half(W2[k * 64 + n]);
    }
  }
}

// ---------------- MFMA GEMM: Y[64 x OUT] per block = X[64 x 128] @ W[128 x OUT] ----------------
template <int OUT>
__global__ __launch_bounds__(256) void gemm_mfma(
    const __half* __restrict__ X, const __half* __restrict__ WT,
    __half* __restrict__ Y, int nrows) {
  constexpr int NT = OUT / 16;
  __shared__ __align__(16) __half Xs[64][136];
  __shared__ __align__(16) __half Ws[OUT][136];
  const int tid = threadIdx.x;
  const int row0 = blockIdx.x * 64;
#pragma unroll
  for (int i = 0; i < 4; i++) {
    int ci = tid + 256 * i;
    int r = ci >> 4, ch = ci & 15;
    int g = row0 + r;
    int4 v = make_int4(0, 0, 0, 0);
    if (g < nrows) v = *(const int4*)&X[(size_t)g * 128 + ch * 8];
    *(int4*)&Xs[r][ch * 8] = v;
  }
#pragma unroll
  for (int i = 0; i < NT; i++) {
    int ci = tid + 256 * i;
    int n = ci >> 4, ch = ci & 15;
    *(int4*)&Ws[n][ch * 8] = *(const int4*)&WT[(size_t)n * 128 + ch * 8];
  }
  __syncthreads();
  const int lane = tid & 63;
  const int w = tid >> 6;
  const int c16 = lane & 15, q = lane >> 4;
  v8h a[4];
#pragma unroll
  for (int kt = 0; kt < 4; kt++)
    a[kt] = *(const v8h*)&Xs[w * 16 + c16][kt * 32 + q * 8];
  v4f acc[NT];
#pragma unroll
  for (int t = 0; t < NT; t++) acc[t] = (v4f){0.f, 0.f, 0.f, 0.f};
#pragma unroll
  for (int t = 0; t < NT; t++) {
#pragma unroll
    for (int kt = 0; kt < 4; kt++) {
      v8h bfr = *(const v8h*)&Ws[t * 16 + c16][kt * 32 + q * 8];
      acc[t] = __builtin_amdgcn_mfma_f32_16x16x32_f16(a[kt], bfr, acc[t], 0, 0, 0);
    }
  }
#pragma unroll
  for (int t = 0; t < NT; t++)
#pragma unroll
    for (int r = 0; r < 4; r++)
      Xs[w * 16 + q * 4 + r][t * 16 + c16] = __float2half(acc[t][r]);
  __syncthreads();
  constexpr int OCH = OUT / 8;
#pragma unroll
  for (int i = 0; i < 64 * OCH / 256; i++) {
    int ci = tid + 256 * i;
    int r = ci / OCH, ch = ci % OCH;
    int g = row0 + r;
    if (g < nrows) *(int4*)&Y[(size_t)g * OUT + ch * 8] = *(const int4*)&Xs[r][ch * 8];
  }
}

// ---------------- mean aggregation (+bias, +optional LN+ReLU) -----------
// 32B/lane (two dwordx4 gathers): F=128 -> LPR=8, 8 edges in flight (16 loads);
// F=64 -> LPR=4, 16 edges in flight. HOUT: fp16 out (GEMM input) vs fp32 out.
template <int F, bool LN, bool HOUT>
__global__ __launch_bounds__(256) void agg_kernel(
    const __half* __restrict__ ft,
    const int* __restrict__ row_ptr, const int* __restrict__ es,
    const float* __restrict__ bias, const float* __restrict__ g,
    const float* __restrict__ beta, void* __restrict__ out_v, int n) {
  int gw = (blockIdx.x * blockDim.x + threadIdx.x) >> 6;
  int lane = threadIdx.x & 63;
  if (gw >= n) return;
  int b = row_ptr[gw], e = row_ptr[gw + 1];
  int deg = e - b;

  constexpr int LPR = F / 16;     // lanes per row (16 halves = 32B each)
  constexpr int EW  = 64 / LPR;   // edges in flight
  const int sub = lane / LPR;
  const int ll  = lane % LPR;
  float acc[16];
#pragma unroll
  for (int q = 0; q < 16; q++) acc[q] = 0.f;

  for (int cb = b; cb < e; cb += 64) {
    int rem = e - cb; if (rem > 64) rem = 64;
    int sn_l = 0;
    if (lane < rem) sn_l = es[cb + lane];
    for (int j = 0; j < rem; j += EW) {
      int jj = j + sub;
      int sn = __shfl(sn_l, jj, 64);
      if (jj < rem) {
        union { float4 f4; __half2 h2[4]; } u0, u1;
        u0.f4 = *(const float4*)&ft[(size_t)sn * F + ll * 16];
        u1.f4 = *(const float4*)&ft[(size_t)sn * F + ll * 16 + 8];
#pragma unroll
        for (int q = 0; q < 4; q++) {
          float2 f0 = __half22float2(u0.h2[q]);
          float2 f1 = __half22float2(u1.h2[q]);
          acc[2 * q + 0] += f0.x;
          acc[2 * q + 1] += f0.y;
          acc[8 + 2 * q + 0] += f1.x;
          acc[8 + 2 * q + 1] += f1.y;
        }
      }
    }
  }

  // combine the EW edge streams (sum over 'sub' lane bits)
#pragma unroll
  for (int o = 32; o >= LPR; o >>= 1)
#pragma unroll
    for (int q = 0; q < 16; q++) acc[q] += __shfl_xor(acc[q], o, 64);

  float sc = (deg > 0) ? (1.0f / (float)deg) : 0.f;
#pragma unroll
  for (int h = 0; h < 4; h++) {
    float4 b4 = *(const float4*)&bias[ll * 16 + h * 4];
    acc[4 * h + 0] = fmaf(acc[4 * h + 0], sc, b4.x);
    acc[4 * h + 1] = fmaf(acc[4 * h + 1], sc, b4.y);
    acc[4 * h + 2] = fmaf(acc[4 * h + 2], sc, b4.z);
    acc[4 * h + 3] = fmaf(acc[4 * h + 3], sc, b4.w);
  }

  if (LN) {
    float sum = 0.f;
#pragma unroll
    for (int q = 0; q < 16; q++) sum += acc[q];
#pragma unroll
    for (int o = LPR / 2; o > 0; o >>= 1) sum += __shfl_xor(sum, o, 64);
    float mean = sum * (1.0f / 128.0f);
    float var = 0.f;
#pragma unroll
    for (int q = 0; q < 16; q++) { acc[q] -= mean; var = fmaf(acc[q], acc[q], var); }
#pragma unroll
    for (int o = LPR / 2; o > 0; o >>= 1) var += __shfl_xor(var, o, 64);
    float r = rsqrtf(var * (1.0f / 128.0f) + 1e-5f);
#pragma unroll
    for (int h = 0; h < 4; h++) {
      float4 g4 = *(const float4*)&g[ll * 16 + h * 4];
      float4 be4 = *(const float4*)&beta[ll * 16 + h * 4];
      acc[4 * h + 0] = fmaxf(acc[4 * h + 0] * r * g4.x + be4.x, 0.f);
      acc[4 * h + 1] = fmaxf(acc[4 * h + 1] * r * g4.y + be4.y, 0.f);
      acc[4 * h + 2] = fmaxf(acc[4 * h + 2] * r * g4.z + be4.z, 0.f);
      acc[4 * h + 3] = fmaxf(acc[4 * h + 3] * r * g4.w + be4.w, 0.f);
    }
  }
  if (sub == 0) {
    if (HOUT) {
      __half* outh = (__half*)out_v;
      union { __half2 h2[4]; int4 i4; } v0, v1;
      v0.h2[0] = __floats2half2_rn(acc[0], acc[1]);
      v0.h2[1] = __floats2half2_rn(acc[2], acc[3]);
      v0.h2[2] = __floats2half2_rn(acc[4], acc[5]);
      v0.h2[3] = __floats2half2_rn(acc[6], acc[7]);
      v1.h2[0] = __floats2half2_rn(acc[8], acc[9]);
      v1.h2[1] = __floats2half2_rn(acc[10], acc[11]);
      v1.h2[2] = __floats2half2_rn(acc[12], acc[13]);
      v1.h2[3] = __floats2half2_rn(acc[14], acc[15]);
      *(int4*)&outh[(size_t)gw * F + ll * 16 + 0] = v0.i4;
      *(int4*)&outh[(size_t)gw * F + ll * 16 + 8] = v1.i4;
    } else {
      float* outf = (float*)out_v;
#pragma unroll
      for (int h = 0; h < 4; h++)
        *(float4*)&outf[(size_t)gw * F + ll * 16 + h * 4] =
            make_float4(acc[4 * h + 0], acc[4 * h + 1], acc[4 * h + 2], acc[4 * h + 3]);
    }
  }
}

// ---------------- bucketed CSR build (proven R8 structure) ----------------
__global__ __launch_bounds__(256) void bhist_kernel(const int* __restrict__ dst,
                                                    int* __restrict__ bhist) {
  __shared__ int hh[256];
  int tid = threadIdx.x;
  hh[tid] = 0;
  __syncthreads();
#pragma unroll
  for (int q = 0; q < 4; q++) {
    int base = blockIdx.x * STILE + q * 1024 + tid * 4;
    if (base + 3 < NE) {
      int4 d = *(const int4*)&dst[base];
      atomicAdd(&hh[d.x >> 8], 1);
      atomicAdd(&hh[d.y >> 8], 1);
      atomicAdd(&hh[d.z >> 8], 1);
      atomicAdd(&hh[d.w >> 8], 1);
    } else {
#pragma unroll
      for (int k = 0; k < 4; k++)
        if (base + k < NE) atomicAdd(&hh[dst[base + k] >> 8], 1);
    }
  }
  __syncthreads();
  if (tid < NB && hh[tid]) atomicAdd(&bhist[tid * CPAD], hh[tid]);
}

__global__ __launch_bounds__(256) void bscan_kernel(const int* __restrict__ bhist,
                                                    int* __restrict__ bucket_base,
                                                    int* __restrict__ bfill) {
  int tid = threadIdx.x;
  int lane = tid & 63, wid = tid >> 6;
  int v = (tid < NB) ? bhist[tid * CPAD] : 0;
  int x = v;
#pragma unroll
  for (int o = 1; o < 64; o <<= 1) {
    int y = __shfl_up(x, o, 64);
    if (lane >= o) x += y;
  }
  __shared__ int wsum[4];
  if (lane == 63) wsum[wid] = x;
  __syncthreads();
  int wpre = 0;
  for (int w = 0; w < wid; w++) wpre += wsum[w];
  int excl = wpre + x - v;
  if (tid < NB) {
    bucket_base[tid] = excl;
    bfill[tid * CPAD] = excl;
  }
  if (tid == 0) bucket_base[NB] = NE;
}

__global__ __launch_bounds__(256) void stage_kernel(const int* __restrict__ src,
                                                    const int* __restrict__ dst,
                                                    int* __restrict__ bfill,
                                                    int* __restrict__ staged) {
  __shared__ int cnt[256];
  __shared__ int basep[256];
  __shared__ int cur[256];
  int tid = threadIdx.x;
  cnt[tid] = 0;
  cur[tid] = 0;
  __syncthreads();
#pragma unroll
  for (int q = 0; q < 4; q++) {
    int base = blockIdx.x * STILE + q * 1024 + tid * 4;
    if (base + 3 < NE) {
      int4 d = *(const int4*)&dst[base];
      atomicAdd(&cnt[d.x >> 8], 1);
      atomicAdd(&cnt[d.y >> 8], 1);
      atomicAdd(&cnt[d.z >> 8], 1);
      atomicAdd(&cnt[d.w >> 8], 1);
    } else {
#pragma unroll
      for (int k = 0; k < 4; k++)
        if (base + k < NE) atomicAdd(&cnt[dst[base + k] >> 8], 1);
    }
  }
  __syncthreads();
  if (tid < NB) basep[tid] = (cnt[tid] > 0) ? atomicAdd(&bfill[tid * CPAD], cnt[tid]) : 0;
  __syncthreads();
#pragma unroll
  for (int q = 0; q < 4; q++) {
    int base = blockIdx.x * STILE + q * 1024 + tid * 4;
    if (base + 3 < NE) {
      int4 d = *(const int4*)&dst[base];
      int4 s = *(const int4*)&src[base];
      int b0 = d.x >> 8, b1 = d.y >> 8, b2 = d.z >> 8, b3 = d.w >> 8;
      int p0 = atomicAdd(&cur[b0], 1);
      staged[basep[b0] + p0] = s.x | ((d.x & 255) << 16);
      int p1 = atomicAdd(&cur[b1], 1);
      staged[basep[b1] + p1] = s.y | ((d.y & 255) << 16);
      int p2 = atomicAdd(&cur[b2], 1);
      staged[basep[b2] + p2] = s.z | ((d.z & 255) << 16);
      int p3 = atomicAdd(&cur[b3], 1);
      staged[basep[b3] + p3] = s.w | ((d.w & 255) << 16);
    } else {
#pragma unroll
      for (int k = 0; k < 4; k++) {
        if (base + k < NE) {
          int d = dst[base + k], s = src[base + k];
          int bb = d >> 8;
          int pp = atomicAdd(&cur[bb], 1);
          staged[basep[bb] + pp] = s | ((d & 255) << 16);
        }
      }
    }
  }
}

__global__ __launch_bounds__(256) void bucket_csr_kernel(const int* __restrict__ staged,
                                                         const int* __restrict__ bucket_base,
                                                         int* __restrict__ row_ptr,
                                                         int* __restrict__ es) {
  int b = blockIdx.x;
  int tid = threadIdx.x;
  int lo = bucket_base[b], hi = bucket_base[b + 1];
  __shared__ int cnt[256];
  __shared__ int fill_l[256];
  __shared__ int wsum[4];
  cnt[tid] = 0;
  __syncthreads();
  for (int i = lo + tid; i < hi; i += 256)
    atomicAdd(&cnt[(staged[i] >> 16) & 255], 1);
  __syncthreads();
  int v = cnt[tid];
  int lane = tid & 63, wid = tid >> 6;
  int x = v;
#pragma unroll
  for (int o = 1; o < 64; o <<= 1) {
    int y = __shfl_up(x, o, 64);
    if (lane >= o) x += y;
  }
  if (lane == 63) wsum[wid] = x;
  __syncthreads();
  int wpre = 0;
  for (int w = 0; w < wid; w++) wpre += wsum[w];
  int start = lo + wpre + x - v;
  int node = (b << 8) + tid;
  if (node < NN) row_ptr[node] = start;
  fill_l[tid] = start;
  __syncthreads();
  for (int i = lo + tid; i < hi; i += 256) {
    int w = staged[i];
    int pos = atomicAdd(&fill_l[(w >> 16) & 255], 1);
    es[pos] = w & 0xFFFF;
  }
  if (b == 0 && tid == 0) row_ptr[NN] = NE;
}

// ---------------- orchestration ----------------
extern "C" void kernel_launch(void* const* d_in, const int* in_sizes, int n_in,
                              void* d_out, int out_size, void* d_ws, size_t ws_size,
                              hipStream_t stream) {
  (void)in_sizes; (void)n_in; (void)out_size; (void)ws_size;
  const float* feat = (const float*)d_in[0];
  const int* src = (const int*)d_in[1];
  const int* dst = (const int*)d_in[2];
  const float* W0 = (const float*)d_in[3];
  const float* b0 = (const float*)d_in[4];
  const float* W1 = (const float*)d_in[5];
  const float* b1 = (const float*)d_in[6];
  const float* W2 = (const float*)d_in[7];
  const float* b2 = (const float*)d_in[8];
  const float* ln1g = (const float*)d_in[9];
  const float* ln1b = (const float*)d_in[10];
  const float* ln2g = (const float*)d_in[11];
  const float* ln2b = (const float*)d_in[12];
  float* out = (float*)d_out;

  char* p = (char*)d_ws;
  auto alloc = [&](size_t bytes) {
    char* r = p;
    p += (bytes + 255) & ~size_t(255);
    return r;
  };
  __half* fth      = (__half*)alloc((size_t)NN * 128 * 2);
  __half* hh       = (__half*)alloc((size_t)NN * 128 * 2);
  __half* feat_h   = (__half*)alloc((size_t)NN * 128 * 2);
  __half* W0T      = (__half*)alloc(128 * 128 * 2);
  __half* W1T      = (__half*)alloc(128 * 128 * 2);
  __half* W2T      = (__half*)alloc(64 * 128 * 2);
  int* row_ptr     = (int*)alloc((size_t)(NN + 1) * 4);
  int* es          = (int*)alloc((size_t)NE * 4);
  int* staged      = (int*)alloc((size_t)NE * 4);
  int* bhist       = (int*)alloc((size_t)NB * CPAD * 4);
  int* bfill       = (int*)alloc((size_t)NB * CPAD * 4);
  int* bucket_base = (int*)alloc((size_t)(NB + 1) * 4);

  // CSR by dst (graph identical for all 3 convs)
  hipMemsetAsync(bhist, 0, (size_t)NB * CPAD * 4, stream);
  int sb = (NE + STILE - 1) / STILE;   // 196 blocks
  bhist_kernel<<<sb, 256, 0, stream>>>(dst, bhist);
  bscan_kernel<<<1, 256, 0, stream>>>(bhist, bucket_base, bfill);
  stage_kernel<<<sb, 256, 0, stream>>>(src, dst, bfill, staged);
  bucket_csr_kernel<<<NB, 256, 0, stream>>>(staged, bucket_base, row_ptr, es);

  // fp16 conversions (feat + transposed weights)
  convert_kernel<<<FEAT_B4 + 160, 256, 0, stream>>>(feat, W0, W1, W2, feat_h, W0T, W1T, W2T);

  int gb = (NN + 63) / 64;     // 782
  int nwb = (NN + 3) / 4;

  gemm_mfma<128><<<gb, 256, 0, stream>>>(feat_h, W0T, fth, NN);
  agg_kernel<128, true, true><<<nwb, 256, 0, stream>>>(fth, row_ptr, es, b0, ln1g, ln1b, hh, NN);
  gemm_mfma<128><<<gb, 256, 0, stream>>>(hh, W1T, fth, NN);
  agg_kernel<128, true, true><<<nwb, 256, 0, stream>>>(fth, row_ptr, es, b1, ln2g, ln2b, hh, NN);
  gemm_mfma<64><<<gb, 256, 0, stream>>>(hh, W2T, fth, NN);
  agg_kernel<64, false, false><<<nwb, 256, 0, stream>>>(fth, row_ptr, es, b2, nullptr, nullptr, out, NN);
}

// Round 11
// 278.627 us; speedup vs baseline: 1.0076x; 1.0076x over previous
//
#include <hip/hip_runtime.h>
#include <hip/hip_fp16.h>
#include <math.h>

#define NN 50000
#define NE 800000
#define KDIM 128
#define NB 196            // dst buckets of 256 nodes: bucket = dst >> 8
#define CPAD 16           // pad global atomic counters to one per 64B line
#define STILE 4096        // edges per stage block

typedef _Float16 v8h __attribute__((ext_vector_type(8)));
typedef float v4f __attribute__((ext_vector_type(4)));

// ---------------- convert: feat -> fp16, W0/W1/W2 -> fp16 transposed [n][k] ----------------
#define FEAT_B4 6250   // NN*128/4 float4 chunks / 256 threads
__global__ __launch_bounds__(256) void convert_kernel(
    const float* __restrict__ feat, const float* __restrict__ W0,
    const float* __restrict__ W1, const float* __restrict__ W2,
    __half* __restrict__ feat_h, __half* __restrict__ W0T,
    __half* __restrict__ W1T, __half* __restrict__ W2T) {
  int b = blockIdx.x;
  int tid = threadIdx.x;
  if (b < FEAT_B4) {
    int i = b * 256 + tid;
    if (i < NN * 32) {
      float4 v = *(const float4*)&feat[(size_t)i * 4];
      union { __half2 h2[2]; int2 i2; } u;
      u.h2[0] = __floats2half2_rn(v.x, v.y);
      u.h2[1] = __floats2half2_rn(v.z, v.w);
      *(int2*)&feat_h[(size_t)i * 4] = u.i2;
    }
  } else {
    int gid = (b - FEAT_B4) * 256 + tid;
    if (gid < 16384) {
      int n = gid >> 7, k = gid & 127;
      W0T[gid] = __float2half(W0[k * 128 + n]);
    } else if (gid < 32768) {
      int g = gid - 16384; int n = g >> 7, k = g & 127;
      W1T[g] = __float2half(W1[k * 128 + n]);
    } else if (gid < 40960) {
      int g = gid - 32768; int n = g >> 7, k = g & 127;   // n<64, k<128
      W2T[g] = __float2half(W2[k * 64 + n]);
    }
  }
}

// ---------------- fused conv (convs 0/1): y = relu(LN(mean_agg(x) @ W + b)) ----------------
// Uses agg<->GEMM commutativity (uniform softmax weights). Block = 64 dst nodes.
// Wave w gather-means rows w*16..w*16+15 (16B/lane, 4 edges in flight) into LDS fp16 tile,
// then MFMA vs WT (B-frags from global, L2-hot 32KB), LN in C-registers, fp16 store.
__global__ __launch_bounds__(256) void fused_conv(
    const __half* __restrict__ X, const __half* __restrict__ WT,
    const int* __restrict__ row_ptr, const int* __restrict__ es,
    const float* __restrict__ bias, const float* __restrict__ g,
    const float* __restrict__ beta, __half* __restrict__ Y, int nrows) {
  __shared__ __align__(16) __half Xs[64][136];
  const int tid = threadIdx.x;
  const int row0 = blockIdx.x * 64;
  const int lane = tid & 63, w = tid >> 6;
  const int sub = lane >> 4, ll = lane & 15;   // 16 lanes/row (16B each), 4 edges in flight

  // ---- gather-mean phase (wave-private rows) ----
  for (int i = 0; i < 16; i++) {
    int node = row0 + w * 16 + i;
    float acc[8];
#pragma unroll
    for (int q2 = 0; q2 < 8; q2++) acc[q2] = 0.f;
    int deg = 0;
    if (node < nrows) {
      int b = row_ptr[node], e = row_ptr[node + 1];
      deg = e - b;
      for (int cb = b; cb < e; cb += 64) {
        int rem = e - cb; if (rem > 64) rem = 64;
        int sn_l = 0;
        if (lane < rem) sn_l = es[cb + lane];
        for (int j = 0; j < rem; j += 4) {
          int jj = j + sub;
          int sn = __shfl(sn_l, jj, 64);
          if (jj < rem) {
            union { float4 f4; __half2 h2[4]; } u;
            u.f4 = *(const float4*)&X[(size_t)sn * 128 + ll * 8];
#pragma unroll
            for (int q2 = 0; q2 < 4; q2++) {
              float2 f = __half22float2(u.h2[q2]);
              acc[2 * q2 + 0] += f.x;
              acc[2 * q2 + 1] += f.y;
            }
          }
        }
      }
#pragma unroll
      for (int o = 32; o >= 16; o >>= 1)
#pragma unroll
        for (int q2 = 0; q2 < 8; q2++) acc[q2] += __shfl_xor(acc[q2], o, 64);
    }
    if (sub == 0) {
      float sc = (deg > 0) ? 1.0f / (float)deg : 0.f;
      union { __half2 h2[4]; int4 i4; } u;
      u.h2[0] = __floats2half2_rn(acc[0] * sc, acc[1] * sc);
      u.h2[1] = __floats2half2_rn(acc[2] * sc, acc[3] * sc);
      u.h2[2] = __floats2half2_rn(acc[4] * sc, acc[5] * sc);
      u.h2[3] = __floats2half2_rn(acc[6] * sc, acc[7] * sc);
      *(int4*)&Xs[w * 16 + i][ll * 8] = u.i4;
    }
  }
  // wave reads only its own rows -> no block barrier needed before MFMA

  // ---- MFMA phase: 16 rows x 128 cols per wave ----
  const int c16 = ll, q = sub;
  v8h a[4];
#pragma unroll
  for (int kt = 0; kt < 4; kt++)
    a[kt] = *(const v8h*)&Xs[w * 16 + c16][kt * 32 + q * 8];
  v4f acc[8];
#pragma unroll
  for (int t = 0; t < 8; t++) acc[t] = (v4f){0.f, 0.f, 0.f, 0.f};
#pragma unroll
  for (int t = 0; t < 8; t++) {
#pragma unroll
    for (int kt = 0; kt < 4; kt++) {
      v8h bfr = *(const v8h*)&WT[(size_t)(t * 16 + c16) * 128 + kt * 32 + q * 8];
      acc[t] = __builtin_amdgcn_mfma_f32_16x16x32_f16(a[kt], bfr, acc[t], 0, 0, 0);
    }
  }

  // ---- epilogue: bias + LN + ReLU. C layout: row = w*16+q*4+r, col = t*16+c16 ----
  float barr[8], garr[8], betr[8];
#pragma unroll
  for (int t = 0; t < 8; t++) {
    barr[t] = bias[t * 16 + c16];
    garr[t] = g[t * 16 + c16];
    betr[t] = beta[t * 16 + c16];
  }
#pragma unroll
  for (int r = 0; r < 4; r++) {
    float s = 0.f;
#pragma unroll
    for (int t = 0; t < 8; t++) { acc[t][r] += barr[t]; s += acc[t][r]; }
#pragma unroll
    for (int o = 1; o <= 8; o <<= 1) s += __shfl_xor(s, o, 64);  // reduce over c16 lanes
    float mu = s * (1.0f / 128.0f);
    float v = 0.f;
#pragma unroll
    for (int t = 0; t < 8; t++) { float d = acc[t][r] - mu; v = fmaf(d, d, v); }
#pragma unroll
    for (int o = 1; o <= 8; o <<= 1) v += __shfl_xor(v, o, 64);
    float rs = rsqrtf(v * (1.0f / 128.0f) + 1e-5f);
#pragma unroll
    for (int t = 0; t < 8; t++)
      acc[t][r] = fmaxf((acc[t][r] - mu) * rs * garr[t] + betr[t], 0.f);
  }

  // ---- fp16 store via LDS bounce ----
#pragma unroll
  for (int t = 0; t < 8; t++)
#pragma unroll
    for (int r = 0; r < 4; r++)
      Xs[w * 16 + q * 4 + r][t * 16 + c16] = __float2half(acc[t][r]);
  __syncthreads();
#pragma unroll
  for (int i = 0; i < 4; i++) {
    int ci = tid + 256 * i;
    int r = ci >> 4, ch = ci & 15;
    int gr = row0 + r;
    if (gr < nrows) *(int4*)&Y[(size_t)gr * 128 + ch * 8] = *(const int4*)&Xs[r][ch * 8];
  }
}

// ---------------- MFMA GEMM (conv2): Y[64 x 64] per block ----------------
template <int OUT>
__global__ __launch_bounds__(256) void gemm_mfma(
    const __half* __restrict__ X, const __half* __restrict__ WT,
    __half* __restrict__ Y, int nrows) {
  constexpr int NT = OUT / 16;
  __shared__ __align__(16) __half Xs[64][136];
  __shared__ __align__(16) __half Ws[OUT][136];
  const int tid = threadIdx.x;
  const int row0 = blockIdx.x * 64;
#pragma unroll
  for (int i = 0; i < 4; i++) {
    int ci = tid + 256 * i;
    int r = ci >> 4, ch = ci & 15;
    int g = row0 + r;
    int4 v = make_int4(0, 0, 0, 0);
    if (g < nrows) v = *(const int4*)&X[(size_t)g * 128 + ch * 8];
    *(int4*)&Xs[r][ch * 8] = v;
  }
#pragma unroll
  for (int i = 0; i < NT; i++) {
    int ci = tid + 256 * i;
    int n = ci >> 4, ch = ci & 15;
    *(int4*)&Ws[n][ch * 8] = *(const int4*)&WT[(size_t)n * 128 + ch * 8];
  }
  __syncthreads();
  const int lane = tid & 63;
  const int w = tid >> 6;
  const int c16 = lane & 15, q = lane >> 4;
  v8h a[4];
#pragma unroll
  for (int kt = 0; kt < 4; kt++)
    a[kt] = *(const v8h*)&Xs[w * 16 + c16][kt * 32 + q * 8];
  v4f acc[NT];
#pragma unroll
  for (int t = 0; t < NT; t++) acc[t] = (v4f){0.f, 0.f, 0.f, 0.f};
#pragma unroll
  for (int t = 0; t < NT; t++) {
#pragma unroll
    for (int kt = 0; kt < 4; kt++) {
      v8h bfr = *(const v8h*)&Ws[t * 16 + c16][kt * 32 + q * 8];
      acc[t] = __builtin_amdgcn_mfma_f32_16x16x32_f16(a[kt], bfr, acc[t], 0, 0, 0);
    }
  }
#pragma unroll
  for (int t = 0; t < NT; t++)
#pragma unroll
    for (int r = 0; r < 4; r++)
      Xs[w * 16 + q * 4 + r][t * 16 + c16] = __float2half(acc[t][r]);
  __syncthreads();
  constexpr int OCH = OUT / 8;
#pragma unroll
  for (int i = 0; i < 64 * OCH / 256; i++) {
    int ci = tid + 256 * i;
    int r = ci / OCH, ch = ci % OCH;
    int g = row0 + r;
    if (g < nrows) *(int4*)&Y[(size_t)g * OUT + ch * 8] = *(const int4*)&Xs[r][ch * 8];
  }
}

// ---------------- mean aggregation, R9-proven 16B/lane (conv2 only: F=64, fp32 out) --------
template <int F, bool LN, bool HOUT>
__global__ __launch_bounds__(256) void agg_kernel(
    const __half* __restrict__ ft,
    const int* __restrict__ row_ptr, const int* __restrict__ es,
    const float* __restrict__ bias, const float* __restrict__ g,
    const float* __restrict__ beta, void* __restrict__ out_v, int n) {
  int gw = (blockIdx.x * blockDim.x + threadIdx.x) >> 6;
  int lane = threadIdx.x & 63;
  if (gw >= n) return;
  int b = row_ptr[gw], e = row_ptr[gw + 1];
  int deg = e - b;

  constexpr int LPR = F / 8;      // lanes per row (8 halves = 16B each)
  constexpr int EW  = 64 / LPR;   // edges in flight
  const int sub = lane / LPR;
  const int ll  = lane % LPR;
  float acc[8];
#pragma unroll
  for (int q = 0; q < 8; q++) acc[q] = 0.f;

  for (int cb = b; cb < e; cb += 64) {
    int rem = e - cb; if (rem > 64) rem = 64;
    int sn_l = 0;
    if (lane < rem) sn_l = es[cb + lane];
    for (int j = 0; j < rem; j += EW) {
      int jj = j + sub;
      int sn = __shfl(sn_l, jj, 64);
      if (jj < rem) {
        union { float4 f4; __half2 h2[4]; } u;
        u.f4 = *(const float4*)&ft[(size_t)sn * F + ll * 8];
#pragma unroll
        for (int q = 0; q < 4; q++) {
          float2 f = __half22float2(u.h2[q]);
          acc[2 * q + 0] += f.x;
          acc[2 * q + 1] += f.y;
        }
      }
    }
  }

#pragma unroll
  for (int o = 32; o >= LPR; o >>= 1)
#pragma unroll
    for (int q = 0; q < 8; q++) acc[q] += __shfl_xor(acc[q], o, 64);

  float sc = (deg > 0) ? (1.0f / (float)deg) : 0.f;
  float4 b4a = *(const float4*)&bias[ll * 8 + 0];
  float4 b4b = *(const float4*)&bias[ll * 8 + 4];
  acc[0] = fmaf(acc[0], sc, b4a.x); acc[1] = fmaf(acc[1], sc, b4a.y);
  acc[2] = fmaf(acc[2], sc, b4a.z); acc[3] = fmaf(acc[3], sc, b4a.w);
  acc[4] = fmaf(acc[4], sc, b4b.x); acc[5] = fmaf(acc[5], sc, b4b.y);
  acc[6] = fmaf(acc[6], sc, b4b.z); acc[7] = fmaf(acc[7], sc, b4b.w);

  if (LN) {
    float sum = 0.f;
#pragma unroll
    for (int q = 0; q < 8; q++) sum += acc[q];
#pragma unroll
    for (int o = LPR / 2; o > 0; o >>= 1) sum += __shfl_xor(sum, o, 64);
    float mean = sum * (1.0f / 128.0f);
    float var = 0.f;
#pragma unroll
    for (int q = 0; q < 8; q++) { acc[q] -= mean; var = fmaf(acc[q], acc[q], var); }
#pragma unroll
    for (int o = LPR / 2; o > 0; o >>= 1) var += __shfl_xor(var, o, 64);
    float r = rsqrtf(var * (1.0f / 128.0f) + 1e-5f);
    float4 g4a = *(const float4*)&g[ll * 8 + 0];
    float4 g4b = *(const float4*)&g[ll * 8 + 4];
    float4 be4a = *(const float4*)&beta[ll * 8 + 0];
    float4 be4b = *(const float4*)&beta[ll * 8 + 4];
    acc[0] = fmaxf(acc[0] * r * g4a.x + be4a.x, 0.f);
    acc[1] = fmaxf(acc[1] * r * g4a.y + be4a.y, 0.f);
    acc[2] = fmaxf(acc[2] * r * g4a.z + be4a.z, 0.f);
    acc[3] = fmaxf(acc[3] * r * g4a.w + be4a.w, 0.f);
    acc[4] = fmaxf(acc[4] * r * g4b.x + be4b.x, 0.f);
    acc[5] = fmaxf(acc[5] * r * g4b.y + be4b.y, 0.f);
    acc[6] = fmaxf(acc[6] * r * g4b.z + be4b.z, 0.f);
    acc[7] = fmaxf(acc[7] * r * g4b.w + be4b.w, 0.f);
  }
  if (sub == 0) {
    if (HOUT) {
      __half* outh = (__half*)out_v;
      union { __half2 h2[4]; int4 i4; } u;
      u.h2[0] = __floats2half2_rn(acc[0], acc[1]);
      u.h2[1] = __floats2half2_rn(acc[2], acc[3]);
      u.h2[2] = __floats2half2_rn(acc[4], acc[5]);
      u.h2[3] = __floats2half2_rn(acc[6], acc[7]);
      *(int4*)&outh[(size_t)gw * F + ll * 8] = u.i4;
    } else {
      float* outf = (float*)out_v;
      *(float4*)&outf[(size_t)gw * F + ll * 8 + 0] = make_float4(acc[0], acc[1], acc[2], acc[3]);
      *(float4*)&outf[(size_t)gw * F + ll * 8 + 4] = make_float4(acc[4], acc[5], acc[6], acc[7]);
    }
  }
}

// ---------------- bucketed CSR build (proven R8 structure) ----------------
__global__ __launch_bounds__(256) void bhist_kernel(const int* __restrict__ dst,
                                                    int* __restrict__ bhist) {
  __shared__ int hh[256];
  int tid = threadIdx.x;
  hh[tid] = 0;
  __syncthreads();
#pragma unroll
  for (int q = 0; q < 4; q++) {
    int base = blockIdx.x * STILE + q * 1024 + tid * 4;
    if (base + 3 < NE) {
      int4 d = *(const int4*)&dst[base];
      atomicAdd(&hh[d.x >> 8], 1);
      atomicAdd(&hh[d.y >> 8], 1);
      atomicAdd(&hh[d.z >> 8], 1);
      atomicAdd(&hh[d.w >> 8], 1);
    } else {
#pragma unroll
      for (int k = 0; k < 4; k++)
        if (base + k < NE) atomicAdd(&hh[dst[base + k] >> 8], 1);
    }
  }
  __syncthreads();
  if (tid < NB && hh[tid]) atomicAdd(&bhist[tid * CPAD], hh[tid]);
}

__global__ __launch_bounds__(256) void bscan_kernel(const int* __restrict__ bhist,
                                                    int* __restrict__ bucket_base,
                                                    int* __restrict__ bfill) {
  int tid = threadIdx.x;
  int lane = tid & 63, wid = tid >> 6;
  int v = (tid < NB) ? bhist[tid * CPAD] : 0;
  int x = v;
#pragma unroll
  for (int o = 1; o < 64; o <<= 1) {
    int y = __shfl_up(x, o, 64);
    if (lane >= o) x += y;
  }
  __shared__ int wsum[4];
  if (lane == 63) wsum[wid] = x;
  __syncthreads();
  int wpre = 0;
  for (int w = 0; w < wid; w++) wpre += wsum[w];
  int excl = wpre + x - v;
  if (tid < NB) {
    bucket_base[tid] = excl;
    bfill[tid * CPAD] = excl;
  }
  if (tid == 0) bucket_base[NB] = NE;
}

__global__ __launch_bounds__(256) void stage_kernel(const int* __restrict__ src,
                                                    const int* __restrict__ dst,
                                                    int* __restrict__ bfill,
                                                    int* __restrict__ staged) {
  __shared__ int cnt[256];
  __shared__ int basep[256];
  __shared__ int cur[256];
  int tid = threadIdx.x;
  cnt[tid] = 0;
  cur[tid] = 0;
  __syncthreads();
#pragma unroll
  for (int q = 0; q < 4; q++) {
    int base = blockIdx.x * STILE + q * 1024 + tid * 4;
    if (base + 3 < NE) {
      int4 d = *(const int4*)&dst[base];
      atomicAdd(&cnt[d.x >> 8], 1);
      atomicAdd(&cnt[d.y >> 8], 1);
      atomicAdd(&cnt[d.z >> 8], 1);
      atomicAdd(&cnt[d.w >> 8], 1);
    } else {
#pragma unroll
      for (int k = 0; k < 4; k++)
        if (base + k < NE) atomicAdd(&cnt[dst[base + k] >> 8], 1);
    }
  }
  __syncthreads();
  if (tid < NB) basep[tid] = (cnt[tid] > 0) ? atomicAdd(&bfill[tid * CPAD], cnt[tid]) : 0;
  __syncthreads();
#pragma unroll
  for (int q = 0; q < 4; q++) {
    int base = blockIdx.x * STILE + q * 1024 + tid * 4;
    if (base + 3 < NE) {
      int4 d = *(const int4*)&dst[base];
      int4 s = *(const int4*)&src[base];
      int b0 = d.x >> 8, b1 = d.y >> 8, b2 = d.z >> 8, b3 = d.w >> 8;
      int p0 = atomicAdd(&cur[b0], 1);
      staged[basep[b0] + p0] = s.x | ((d.x & 255) << 16);
      int p1 = atomicAdd(&cur[b1], 1);
      staged[basep[b1] + p1] = s.y | ((d.y & 255) << 16);
      int p2 = atomicAdd(&cur[b2], 1);
      staged[basep[b2] + p2] = s.z | ((d.z & 255) << 16);
      int p3 = atomicAdd(&cur[b3], 1);
      staged[basep[b3] + p3] = s.w | ((d.w & 255) << 16);
    } else {
#pragma unroll
      for (int k = 0; k < 4; k++) {
        if (base + k < NE) {
          int d = dst[base + k], s = src[base + k];
          int bb = d >> 8;
          int pp = atomicAdd(&cur[bb], 1);
          staged[basep[bb] + pp] = s | ((d & 255) << 16);
        }
      }
    }
  }
}

__global__ __launch_bounds__(256) void bucket_csr_kernel(const int* __restrict__ staged,
                                                         const int* __restrict__ bucket_base,
                                                         int* __restrict__ row_ptr,
                                                         int* __restrict__ es) {
  int b = blockIdx.x;
  int tid = threadIdx.x;
  int lo = bucket_base[b], hi = bucket_base[b + 1];
  __shared__ int cnt[256];
  __shared__ int fill_l[256];
  __shared__ int wsum[4];
  cnt[tid] = 0;
  __syncthreads();
  for (int i = lo + tid; i < hi; i += 256)
    atomicAdd(&cnt[(staged[i] >> 16) & 255], 1);
  __syncthreads();
  int v = cnt[tid];
  int lane = tid & 63, wid = tid >> 6;
  int x = v;
#pragma unroll
  for (int o = 1; o < 64; o <<= 1) {
    int y = __shfl_up(x, o, 64);
    if (lane >= o) x += y;
  }
  if (lane == 63) wsum[wid] = x;
  __syncthreads();
  int wpre = 0;
  for (int w = 0; w < wid; w++) wpre += wsum[w];
  int start = lo + wpre + x - v;
  int node = (b << 8) + tid;
  if (node < NN) row_ptr[node] = start;
  fill_l[tid] = start;
  __syncthreads();
  for (int i = lo + tid; i < hi; i += 256) {
    int w = staged[i];
    int pos = atomicAdd(&fill_l[(w >> 16) & 255], 1);
    es[pos] = w & 0xFFFF;
  }
  if (b == 0 && tid == 0) row_ptr[NN] = NE;
}

// ---------------- orchestration ----------------
extern "C" void kernel_launch(void* const* d_in, const int* in_sizes, int n_in,
                              void* d_out, int out_size, void* d_ws, size_t ws_size,
                              hipStream_t stream) {
  (void)in_sizes; (void)n_in; (void)out_size; (void)ws_size;
  const float* feat = (const float*)d_in[0];
  const int* src = (const int*)d_in[1];
  const int* dst = (const int*)d_in[2];
  const float* W0 = (const float*)d_in[3];
  const float* b0 = (const float*)d_in[4];
  const float* W1 = (const float*)d_in[5];
  const float* b1 = (const float*)d_in[6];
  const float* W2 = (const float*)d_in[7];
  const float* b2 = (const float*)d_in[8];
  const float* ln1g = (const float*)d_in[9];
  const float* ln1b = (const float*)d_in[10];
  const float* ln2g = (const float*)d_in[11];
  const float* ln2b = (const float*)d_in[12];
  float* out = (float*)d_out;

  char* p = (char*)d_ws;
  auto alloc = [&](size_t bytes) {
    char* r = p;
    p += (bytes + 255) & ~size_t(255);
    return r;
  };
  __half* feat_h   = (__half*)alloc((size_t)NN * 128 * 2);
  __half* x1       = (__half*)alloc((size_t)NN * 128 * 2);
  __half* x2       = (__half*)alloc((size_t)NN * 128 * 2);
  __half* ft2      = (__half*)alloc((size_t)NN * 64 * 2);
  __half* W0T      = (__half*)alloc(128 * 128 * 2);
  __half* W1T      = (__half*)alloc(128 * 128 * 2);
  __half* W2T      = (__half*)alloc(64 * 128 * 2);
  int* row_ptr     = (int*)alloc((size_t)(NN + 1) * 4);
  int* es          = (int*)alloc((size_t)NE * 4);
  int* staged      = (int*)alloc((size_t)NE * 4);
  int* bhist       = (int*)alloc((size_t)NB * CPAD * 4);
  int* bfill       = (int*)alloc((size_t)NB * CPAD * 4);
  int* bucket_base = (int*)alloc((size_t)(NB + 1) * 4);

  // CSR by dst (graph identical for all 3 convs)
  hipMemsetAsync(bhist, 0, (size_t)NB * CPAD * 4, stream);
  int sb = (NE + STILE - 1) / STILE;   // 196 blocks
  bhist_kernel<<<sb, 256, 0, stream>>>(dst, bhist);
  bscan_kernel<<<1, 256, 0, stream>>>(bhist, bucket_base, bfill);
  stage_kernel<<<sb, 256, 0, stream>>>(src, dst, bfill, staged);
  bucket_csr_kernel<<<NB, 256, 0, stream>>>(staged, bucket_base, row_ptr, es);

  // fp16 conversions (feat + transposed weights)
  convert_kernel<<<FEAT_B4 + 160, 256, 0, stream>>>(feat, W0, W1, W2, feat_h, W0T, W1T, W2T);

  int gb = (NN + 63) / 64;     // 782
  int nwb = (NN + 3) / 4;

  // conv0 + conv1: fused gather-mean -> MFMA -> bias+LN+ReLU
  fused_conv<<<gb, 256, 0, stream>>>(feat_h, W0T, row_ptr, es, b0, ln1g, ln1b, x1, NN);
  fused_conv<<<gb, 256, 0, stream>>>(x1, W1T, row_ptr, es, b1, ln2g, ln2b, x2, NN);
  // conv2: GEMM (64-dim out) then mean agg (gather on the cheaper 64-dim rows)
  gemm_mfma<64><<<gb, 256, 0, stream>>>(x2, W2T, ft2, NN);
  agg_kernel<64, false, false><<<nwb, 256, 0, stream>>>(ft2, row_ptr, es, b2, nullptr, nullptr, out, NN);
}

// Round 12
// 252.534 us; speedup vs baseline: 1.1118x; 1.1033x over previous
//
#include <hip/hip_runtime.h>
#include <hip/hip_fp16.h>
#include <math.h>

#define NN 50000
#define NE 800000
#define NB 196            // dst buckets of 256 nodes: bucket = dst >> 8
#define CPAD 16           // pad global atomic counters to one per 64B line
#define STILE 4096        // edges per stage block

typedef _Float16 v8h __attribute__((ext_vector_type(8)));
typedef float v4f __attribute__((ext_vector_type(4)));

// ---------------- convert: W0/W1/W2 -> fp16 transposed [n][k]; also zeros bhist ----------------
__global__ __launch_bounds__(256) void convert_kernel(
    const float* __restrict__ W0, const float* __restrict__ W1,
    const float* __restrict__ W2, __half* __restrict__ W0T,
    __half* __restrict__ W1T, __half* __restrict__ W2T,
    int* __restrict__ bhist) {
  int gid = blockIdx.x * 256 + threadIdx.x;
  if (gid < NB * CPAD) bhist[gid] = 0;
  if (gid < 16384) {
    int n = gid >> 7, k = gid & 127;
    W0T[gid] = __float2half(W0[k * 128 + n]);
  } else if (gid < 32768) {
    int g = gid - 16384; int n = g >> 7, k = g & 127;
    W1T[g] = __float2half(W1[k * 128 + n]);
  } else if (gid < 40960) {
    int g = gid - 32768; int n = g >> 7, k = g & 127;   // n<64, k<128
    W2T[g] = __float2half(W2[k * 64 + n]);
  }
}

// ---------------- MFMA GEMM: Y[64 x OUT] per block = X[64 x 128] @ W[128 x OUT] ----------------
// F32IN: stage fp32 input with inline fp16 convert (conv0 reads feat directly).
template <int OUT, bool F32IN>
__global__ __launch_bounds__(256) void gemm_mfma(
    const void* __restrict__ Xv, const __half* __restrict__ WT,
    __half* __restrict__ Y, int nrows) {
  constexpr int NT = OUT / 16;
  __shared__ __align__(16) __half Xs[64][136];
  __shared__ __align__(16) __half Ws[OUT][136];
  const int tid = threadIdx.x;
  const int row0 = blockIdx.x * 64;
#pragma unroll
  for (int i = 0; i < 4; i++) {
    int ci = tid + 256 * i;
    int r = ci >> 4, ch = ci & 15;
    int g = row0 + r;
    if (F32IN) {
      const float* X32 = (const float*)Xv;
      float4 a0 = make_float4(0.f, 0.f, 0.f, 0.f), a1 = a0;
      if (g < nrows) {
        a0 = *(const float4*)&X32[(size_t)g * 128 + ch * 8];
        a1 = *(const float4*)&X32[(size_t)g * 128 + ch * 8 + 4];
      }
      union { __half2 h2[4]; int4 i4; } u;
      u.h2[0] = __floats2half2_rn(a0.x, a0.y);
      u.h2[1] = __floats2half2_rn(a0.z, a0.w);
      u.h2[2] = __floats2half2_rn(a1.x, a1.y);
      u.h2[3] = __floats2half2_rn(a1.z, a1.w);
      *(int4*)&Xs[r][ch * 8] = u.i4;
    } else {
      const __half* X16 = (const __half*)Xv;
      int4 v = make_int4(0, 0, 0, 0);
      if (g < nrows) v = *(const int4*)&X16[(size_t)g * 128 + ch * 8];
      *(int4*)&Xs[r][ch * 8] = v;
    }
  }
#pragma unroll
  for (int i = 0; i < NT; i++) {
    int ci = tid + 256 * i;
    int n = ci >> 4, ch = ci & 15;
    *(int4*)&Ws[n][ch * 8] = *(const int4*)&WT[(size_t)n * 128 + ch * 8];
  }
  __syncthreads();
  const int lane = tid & 63;
  const int w = tid >> 6;
  const int c16 = lane & 15, q = lane >> 4;
  v8h a[4];
#pragma unroll
  for (int kt = 0; kt < 4; kt++)
    a[kt] = *(const v8h*)&Xs[w * 16 + c16][kt * 32 + q * 8];
  v4f acc[NT];
#pragma unroll
  for (int t = 0; t < NT; t++) acc[t] = (v4f){0.f, 0.f, 0.f, 0.f};
#pragma unroll
  for (int t = 0; t < NT; t++) {
#pragma unroll
    for (int kt = 0; kt < 4; kt++) {
      v8h bfr = *(const v8h*)&Ws[t * 16 + c16][kt * 32 + q * 8];
      acc[t] = __builtin_amdgcn_mfma_f32_16x16x32_f16(a[kt], bfr, acc[t], 0, 0, 0);
    }
  }
#pragma unroll
  for (int t = 0; t < NT; t++)
#pragma unroll
    for (int r = 0; r < 4; r++)
      Xs[w * 16 + q * 4 + r][t * 16 + c16] = __float2half(acc[t][r]);
  __syncthreads();
  constexpr int OCH = OUT / 8;
#pragma unroll
  for (int i = 0; i < 64 * OCH / 256; i++) {
    int ci = tid + 256 * i;
    int r = ci / OCH, ch = ci % OCH;
    int g = row0 + r;
    if (g < nrows) *(int4*)&Y[(size_t)g * OUT + ch * 8] = *(const int4*)&Xs[r][ch * 8];
  }
}

// ---------------- mean aggregation (+bias, +optional LN+ReLU), R9-proven 16B/lane ----------
template <int F, bool LN, bool HOUT>
__global__ __launch_bounds__(256) void agg_kernel(
    const __half* __restrict__ ft,
    const int* __restrict__ row_ptr, const unsigned short* __restrict__ es,
    const float* __restrict__ bias, const float* __restrict__ g,
    const float* __restrict__ beta, void* __restrict__ out_v, int n) {
  int gw = (blockIdx.x * blockDim.x + threadIdx.x) >> 6;
  int lane = threadIdx.x & 63;
  if (gw >= n) return;
  int b = row_ptr[gw], e = row_ptr[gw + 1];
  int deg = e - b;

  constexpr int LPR = F / 8;      // lanes per row (8 halves = 16B each)
  constexpr int EW  = 64 / LPR;   // edges in flight
  const int sub = lane / LPR;
  const int ll  = lane % LPR;
  float acc[8];
#pragma unroll
  for (int q = 0; q < 8; q++) acc[q] = 0.f;

  for (int cb = b; cb < e; cb += 64) {
    int rem = e - cb; if (rem > 64) rem = 64;
    int sn_l = 0;
    if (lane < rem) sn_l = es[cb + lane];
    for (int j = 0; j < rem; j += EW) {
      int jj = j + sub;
      int sn = __shfl(sn_l, jj, 64);
      if (jj < rem) {
        union { float4 f4; __half2 h2[4]; } u;
        u.f4 = *(const float4*)&ft[(size_t)sn * F + ll * 8];
#pragma unroll
        for (int q = 0; q < 4; q++) {
          float2 f = __half22float2(u.h2[q]);
          acc[2 * q + 0] += f.x;
          acc[2 * q + 1] += f.y;
        }
      }
    }
  }

#pragma unroll
  for (int o = 32; o >= LPR; o >>= 1)
#pragma unroll
    for (int q = 0; q < 8; q++) acc[q] += __shfl_xor(acc[q], o, 64);

  float sc = (deg > 0) ? (1.0f / (float)deg) : 0.f;
  float4 b4a = *(const float4*)&bias[ll * 8 + 0];
  float4 b4b = *(const float4*)&bias[ll * 8 + 4];
  acc[0] = fmaf(acc[0], sc, b4a.x); acc[1] = fmaf(acc[1], sc, b4a.y);
  acc[2] = fmaf(acc[2], sc, b4a.z); acc[3] = fmaf(acc[3], sc, b4a.w);
  acc[4] = fmaf(acc[4], sc, b4b.x); acc[5] = fmaf(acc[5], sc, b4b.y);
  acc[6] = fmaf(acc[6], sc, b4b.z); acc[7] = fmaf(acc[7], sc, b4b.w);

  if (LN) {
    float sum = 0.f;
#pragma unroll
    for (int q = 0; q < 8; q++) sum += acc[q];
#pragma unroll
    for (int o = LPR / 2; o > 0; o >>= 1) sum += __shfl_xor(sum, o, 64);
    float mean = sum * (1.0f / 128.0f);
    float var = 0.f;
#pragma unroll
    for (int q = 0; q < 8; q++) { acc[q] -= mean; var = fmaf(acc[q], acc[q], var); }
#pragma unroll
    for (int o = LPR / 2; o > 0; o >>= 1) var += __shfl_xor(var, o, 64);
    float r = rsqrtf(var * (1.0f / 128.0f) + 1e-5f);
    float4 g4a = *(const float4*)&g[ll * 8 + 0];
    float4 g4b = *(const float4*)&g[ll * 8 + 4];
    float4 be4a = *(const float4*)&beta[ll * 8 + 0];
    float4 be4b = *(const float4*)&beta[ll * 8 + 4];
    acc[0] = fmaxf(acc[0] * r * g4a.x + be4a.x, 0.f);
    acc[1] = fmaxf(acc[1] * r * g4a.y + be4a.y, 0.f);
    acc[2] = fmaxf(acc[2] * r * g4a.z + be4a.z, 0.f);
    acc[3] = fmaxf(acc[3] * r * g4a.w + be4a.w, 0.f);
    acc[4] = fmaxf(acc[4] * r * g4b.x + be4b.x, 0.f);
    acc[5] = fmaxf(acc[5] * r * g4b.y + be4b.y, 0.f);
    acc[6] = fmaxf(acc[6] * r * g4b.z + be4b.z, 0.f);
    acc[7] = fmaxf(acc[7] * r * g4b.w + be4b.w, 0.f);
  }
  if (sub == 0) {
    if (HOUT) {
      __half* outh = (__half*)out_v;
      union { __half2 h2[4]; int4 i4; } u;
      u.h2[0] = __floats2half2_rn(acc[0], acc[1]);
      u.h2[1] = __floats2half2_rn(acc[2], acc[3]);
      u.h2[2] = __floats2half2_rn(acc[4], acc[5]);
      u.h2[3] = __floats2half2_rn(acc[6], acc[7]);
      *(int4*)&outh[(size_t)gw * F + ll * 8] = u.i4;
    } else {
      float* outf = (float*)out_v;
      *(float4*)&outf[(size_t)gw * F + ll * 8 + 0] = make_float4(acc[0], acc[1], acc[2], acc[3]);
      *(float4*)&outf[(size_t)gw * F + ll * 8 + 4] = make_float4(acc[4], acc[5], acc[6], acc[7]);
    }
  }
}

// ---------------- bucketed CSR build (proven R8 structure; es -> ushort) ----------------
__global__ __launch_bounds__(256) void bhist_kernel(const int* __restrict__ dst,
                                                    int* __restrict__ bhist) {
  __shared__ int hh[256];
  int tid = threadIdx.x;
  hh[tid] = 0;
  __syncthreads();
#pragma unroll
  for (int q = 0; q < 4; q++) {
    int base = blockIdx.x * STILE + q * 1024 + tid * 4;
    if (base + 3 < NE) {
      int4 d = *(const int4*)&dst[base];
      atomicAdd(&hh[d.x >> 8], 1);
      atomicAdd(&hh[d.y >> 8], 1);
      atomicAdd(&hh[d.z >> 8], 1);
      atomicAdd(&hh[d.w >> 8], 1);
    } else {
#pragma unroll
      for (int k = 0; k < 4; k++)
        if (base + k < NE) atomicAdd(&hh[dst[base + k] >> 8], 1);
    }
  }
  __syncthreads();
  if (tid < NB && hh[tid]) atomicAdd(&bhist[tid * CPAD], hh[tid]);
}

__global__ __launch_bounds__(256) void bscan_kernel(const int* __restrict__ bhist,
                                                    int* __restrict__ bucket_base,
                                                    int* __restrict__ bfill) {
  int tid = threadIdx.x;
  int lane = tid & 63, wid = tid >> 6;
  int v = (tid < NB) ? bhist[tid * CPAD] : 0;
  int x = v;
#pragma unroll
  for (int o = 1; o < 64; o <<= 1) {
    int y = __shfl_up(x, o, 64);
    if (lane >= o) x += y;
  }
  __shared__ int wsum[4];
  if (lane == 63) wsum[wid] = x;
  __syncthreads();
  int wpre = 0;
  for (int w = 0; w < wid; w++) wpre += wsum[w];
  int excl = wpre + x - v;
  if (tid < NB) {
    bucket_base[tid] = excl;
    bfill[tid * CPAD] = excl;
  }
  if (tid == 0) bucket_base[NB] = NE;
}

__global__ __launch_bounds__(256) void stage_kernel(const int* __restrict__ src,
                                                    const int* __restrict__ dst,
                                                    int* __restrict__ bfill,
                                                    int* __restrict__ staged) {
  __shared__ int cnt[256];
  __shared__ int basep[256];
  __shared__ int cur[256];
  int tid = threadIdx.x;
  cnt[tid] = 0;
  cur[tid] = 0;
  __syncthreads();
#pragma unroll
  for (int q = 0; q < 4; q++) {
    int base = blockIdx.x * STILE + q * 1024 + tid * 4;
    if (base + 3 < NE) {
      int4 d = *(const int4*)&dst[base];
      atomicAdd(&cnt[d.x >> 8], 1);
      atomicAdd(&cnt[d.y >> 8], 1);
      atomicAdd(&cnt[d.z >> 8], 1);
      atomicAdd(&cnt[d.w >> 8], 1);
    } else {
#pragma unroll
      for (int k = 0; k < 4; k++)
        if (base + k < NE) atomicAdd(&cnt[dst[base + k] >> 8], 1);
    }
  }
  __syncthreads();
  if (tid < NB) basep[tid] = (cnt[tid] > 0) ? atomicAdd(&bfill[tid * CPAD], cnt[tid]) : 0;
  __syncthreads();
#pragma unroll
  for (int q = 0; q < 4; q++) {
    int base = blockIdx.x * STILE + q * 1024 + tid * 4;
    if (base + 3 < NE) {
      int4 d = *(const int4*)&dst[base];
      int4 s = *(const int4*)&src[base];
      int b0 = d.x >> 8, b1 = d.y >> 8, b2 = d.z >> 8, b3 = d.w >> 8;
      int p0 = atomicAdd(&cur[b0], 1);
      staged[basep[b0] + p0] = s.x | ((d.x & 255) << 16);
      int p1 = atomicAdd(&cur[b1], 1);
      staged[basep[b1] + p1] = s.y | ((d.y & 255) << 16);
      int p2 = atomicAdd(&cur[b2], 1);
      staged[basep[b2] + p2] = s.z | ((d.z & 255) << 16);
      int p3 = atomicAdd(&cur[b3], 1);
      staged[basep[b3] + p3] = s.w | ((d.w & 255) << 16);
    } else {
#pragma unroll
      for (int k = 0; k < 4; k++) {
        if (base + k < NE) {
          int d = dst[base + k], s = src[base + k];
          int bb = d >> 8;
          int pp = atomicAdd(&cur[bb], 1);
          staged[basep[bb] + pp] = s | ((d & 255) << 16);
        }
      }
    }
  }
}

__global__ __launch_bounds__(256) void bucket_csr_kernel(const int* __restrict__ staged,
                                                         const int* __restrict__ bucket_base,
                                                         int* __restrict__ row_ptr,
                                                         unsigned short* __restrict__ es) {
  int b = blockIdx.x;
  int tid = threadIdx.x;
  int lo = bucket_base[b], hi = bucket_base[b + 1];
  __shared__ int cnt[256];
  __shared__ int fill_l[256];
  __shared__ int wsum[4];
  cnt[tid] = 0;
  __syncthreads();
  for (int i = lo + tid; i < hi; i += 256)
    atomicAdd(&cnt[(staged[i] >> 16) & 255], 1);
  __syncthreads();
  int v = cnt[tid];
  int lane = tid & 63, wid = tid >> 6;
  int x = v;
#pragma unroll
  for (int o = 1; o < 64; o <<= 1) {
    int y = __shfl_up(x, o, 64);
    if (lane >= o) x += y;
  }
  if (lane == 63) wsum[wid] = x;
  __syncthreads();
  int wpre = 0;
  for (int w = 0; w < wid; w++) wpre += wsum[w];
  int start = lo + wpre + x - v;
  int node = (b << 8) + tid;
  if (node < NN) row_ptr[node] = start;
  fill_l[tid] = start;
  __syncthreads();
  for (int i = lo + tid; i < hi; i += 256) {
    int w = staged[i];
    int pos = atomicAdd(&fill_l[(w >> 16) & 255], 1);
    es[pos] = (unsigned short)(w & 0xFFFF);
  }
  if (b == 0 && tid == 0) row_ptr[NN] = NE;
}

// ---------------- orchestration ----------------
extern "C" void kernel_launch(void* const* d_in, const int* in_sizes, int n_in,
                              void* d_out, int out_size, void* d_ws, size_t ws_size,
                              hipStream_t stream) {
  (void)in_sizes; (void)n_in; (void)out_size; (void)ws_size;
  const float* feat = (const float*)d_in[0];
  const int* src = (const int*)d_in[1];
  const int* dst = (const int*)d_in[2];
  const float* W0 = (const float*)d_in[3];
  const float* b0 = (const float*)d_in[4];
  const float* W1 = (const float*)d_in[5];
  const float* b1 = (const float*)d_in[6];
  const float* W2 = (const float*)d_in[7];
  const float* b2 = (const float*)d_in[8];
  const float* ln1g = (const float*)d_in[9];
  const float* ln1b = (const float*)d_in[10];
  const float* ln2g = (const float*)d_in[11];
  const float* ln2b = (const float*)d_in[12];
  float* out = (float*)d_out;

  char* p = (char*)d_ws;
  auto alloc = [&](size_t bytes) {
    char* r = p;
    p += (bytes + 255) & ~size_t(255);
    return r;
  };
  __half* fth      = (__half*)alloc((size_t)NN * 128 * 2);
  __half* hh       = (__half*)alloc((size_t)NN * 128 * 2);
  __half* W0T      = (__half*)alloc(128 * 128 * 2);
  __half* W1T      = (__half*)alloc(128 * 128 * 2);
  __half* W2T      = (__half*)alloc(64 * 128 * 2);
  int* row_ptr     = (int*)alloc((size_t)(NN + 1) * 4);
  unsigned short* es = (unsigned short*)alloc((size_t)NE * 2);
  int* staged      = (int*)alloc((size_t)NE * 4);
  int* bhist       = (int*)alloc((size_t)NB * CPAD * 4);
  int* bfill       = (int*)alloc((size_t)NB * CPAD * 4);
  int* bucket_base = (int*)alloc((size_t)(NB + 1) * 4);

  // convert weights + zero bhist (replaces memset dispatch)
  convert_kernel<<<160, 256, 0, stream>>>(W0, W1, W2, W0T, W1T, W2T, bhist);

  // CSR by dst (graph identical for all 3 convs)
  int sb = (NE + STILE - 1) / STILE;   // 196 blocks
  bhist_kernel<<<sb, 256, 0, stream>>>(dst, bhist);
  bscan_kernel<<<1, 256, 0, stream>>>(bhist, bucket_base, bfill);
  stage_kernel<<<sb, 256, 0, stream>>>(src, dst, bfill, staged);
  bucket_csr_kernel<<<NB, 256, 0, stream>>>(staged, bucket_base, row_ptr, es);

  int gb = (NN + 63) / 64;     // 782
  int nwb = (NN + 3) / 4;

  gemm_mfma<128, true><<<gb, 256, 0, stream>>>(feat, W0T, fth, NN);
  agg_kernel<128, true, true><<<nwb, 256, 0, stream>>>(fth, row_ptr, es, b0, ln1g, ln1b, hh, NN);
  gemm_mfma<128, false><<<gb, 256, 0, stream>>>(hh, W1T, fth, NN);
  agg_kernel<128, true, true><<<nwb, 256, 0, stream>>>(fth, row_ptr, es, b1, ln2g, ln2b, hh, NN);
  gemm_mfma<64, false><<<gb, 256, 0, stream>>>(hh, W2T, fth, NN);
  agg_kernel<64, false, false><<<nwb, 256, 0, stream>>>(fth, row_ptr, es, b2, nullptr, nullptr, out, NN);
}

// Round 13
// 240.676 us; speedup vs baseline: 1.1665x; 1.0493x over previous
//
#include <hip/hip_runtime.h>
#include <hip/hip_fp16.h>
#include <math.h>

#define NN 50000
#define NE 800000
#define NB 196            // dst buckets of 256 nodes: bucket = dst >> 8
#define CPAD 16           // pad global atomic counters to one per 64B line
#define STILE 4096        // edges per stage block
#define BCAP 8192         // staged slots per bucket (avg occupancy 4081, Binomial std ~64)

typedef _Float16 v8h __attribute__((ext_vector_type(8)));
typedef float v4f __attribute__((ext_vector_type(4)));

// ---------------- convert: W0/W1/W2 -> fp16 transposed [n][k]; also zeros bhist ----------------
__global__ __launch_bounds__(256) void convert_kernel(
    const float* __restrict__ W0, const float* __restrict__ W1,
    const float* __restrict__ W2, __half* __restrict__ W0T,
    __half* __restrict__ W1T, __half* __restrict__ W2T,
    int* __restrict__ bhist) {
  int gid = blockIdx.x * 256 + threadIdx.x;
  if (gid < NB * CPAD) bhist[gid] = 0;
  if (gid < 16384) {
    int n = gid >> 7, k = gid & 127;
    W0T[gid] = __float2half(W0[k * 128 + n]);
  } else if (gid < 32768) {
    int g = gid - 16384; int n = g >> 7, k = g & 127;
    W1T[g] = __float2half(W1[k * 128 + n]);
  } else if (gid < 40960) {
    int g = gid - 32768; int n = g >> 7, k = g & 127;   // n<64, k<128
    W2T[g] = __float2half(W2[k * 64 + n]);
  }
}

// ---------------- MFMA GEMM: Y[64 x OUT] per block = X[64 x 128] @ W[128 x OUT] ----------------
template <int OUT, bool F32IN>
__global__ __launch_bounds__(256) void gemm_mfma(
    const void* __restrict__ Xv, const __half* __restrict__ WT,
    __half* __restrict__ Y, int nrows) {
  constexpr int NT = OUT / 16;
  __shared__ __align__(16) __half Xs[64][136];
  __shared__ __align__(16) __half Ws[OUT][136];
  const int tid = threadIdx.x;
  const int row0 = blockIdx.x * 64;
#pragma unroll
  for (int i = 0; i < 4; i++) {
    int ci = tid + 256 * i;
    int r = ci >> 4, ch = ci & 15;
    int g = row0 + r;
    if (F32IN) {
      const float* X32 = (const float*)Xv;
      float4 a0 = make_float4(0.f, 0.f, 0.f, 0.f), a1 = a0;
      if (g < nrows) {
        a0 = *(const float4*)&X32[(size_t)g * 128 + ch * 8];
        a1 = *(const float4*)&X32[(size_t)g * 128 + ch * 8 + 4];
      }
      union { __half2 h2[4]; int4 i4; } u;
      u.h2[0] = __floats2half2_rn(a0.x, a0.y);
      u.h2[1] = __floats2half2_rn(a0.z, a0.w);
      u.h2[2] = __floats2half2_rn(a1.x, a1.y);
      u.h2[3] = __floats2half2_rn(a1.z, a1.w);
      *(int4*)&Xs[r][ch * 8] = u.i4;
    } else {
      const __half* X16 = (const __half*)Xv;
      int4 v = make_int4(0, 0, 0, 0);
      if (g < nrows) v = *(const int4*)&X16[(size_t)g * 128 + ch * 8];
      *(int4*)&Xs[r][ch * 8] = v;
    }
  }
#pragma unroll
  for (int i = 0; i < NT; i++) {
    int ci = tid + 256 * i;
    int n = ci >> 4, ch = ci & 15;
    *(int4*)&Ws[n][ch * 8] = *(const int4*)&WT[(size_t)n * 128 + ch * 8];
  }
  __syncthreads();
  const int lane = tid & 63;
  const int w = tid >> 6;
  const int c16 = lane & 15, q = lane >> 4;
  v8h a[4];
#pragma unroll
  for (int kt = 0; kt < 4; kt++)
    a[kt] = *(const v8h*)&Xs[w * 16 + c16][kt * 32 + q * 8];
  v4f acc[NT];
#pragma unroll
  for (int t = 0; t < NT; t++) acc[t] = (v4f){0.f, 0.f, 0.f, 0.f};
#pragma unroll
  for (int t = 0; t < NT; t++) {
#pragma unroll
    for (int kt = 0; kt < 4; kt++) {
      v8h bfr = *(const v8h*)&Ws[t * 16 + c16][kt * 32 + q * 8];
      acc[t] = __builtin_amdgcn_mfma_f32_16x16x32_f16(a[kt], bfr, acc[t], 0, 0, 0);
    }
  }
#pragma unroll
  for (int t = 0; t < NT; t++)
#pragma unroll
    for (int r = 0; r < 4; r++)
      Xs[w * 16 + q * 4 + r][t * 16 + c16] = __float2half(acc[t][r]);
  __syncthreads();
  constexpr int OCH = OUT / 8;
#pragma unroll
  for (int i = 0; i < 64 * OCH / 256; i++) {
    int ci = tid + 256 * i;
    int r = ci / OCH, ch = ci % OCH;
    int g = row0 + r;
    if (g < nrows) *(int4*)&Y[(size_t)g * OUT + ch * 8] = *(const int4*)&Xs[r][ch * 8];
  }
}

// ---------------- mean aggregation (+bias, +optional LN+ReLU) -----------
// 16B/lane, fp16 PACKED accumulation (v_pk_add_f16): error lands in the SUM and is
// divided by deg afterwards -> ~1e-3 in the mean, negligible. 4 pk_adds per load vs
// 16 cvt+add before. fp32 only in the epilogue.
template <int F, bool LN, bool HOUT>
__global__ __launch_bounds__(256) void agg_kernel(
    const __half* __restrict__ ft,
    const int* __restrict__ row_ptr, const unsigned short* __restrict__ es,
    const float* __restrict__ bias, const float* __restrict__ g,
    const float* __restrict__ beta, void* __restrict__ out_v, int n) {
  int gw = (blockIdx.x * blockDim.x + threadIdx.x) >> 6;
  int lane = threadIdx.x & 63;
  if (gw >= n) return;
  int b = row_ptr[gw], e = row_ptr[gw + 1];
  int deg = e - b;

  constexpr int LPR = F / 8;      // lanes per row (8 halves = 16B each)
  constexpr int EW  = 64 / LPR;   // edges in flight
  const int sub = lane / LPR;
  const int ll  = lane % LPR;
  __half2 hacc[4];
#pragma unroll
  for (int q = 0; q < 4; q++) hacc[q] = __floats2half2_rn(0.f, 0.f);

  for (int cb = b; cb < e; cb += 64) {
    int rem = e - cb; if (rem > 64) rem = 64;
    int sn_l = 0;
    if (lane < rem) sn_l = es[cb + lane];
    for (int j = 0; j < rem; j += EW) {
      int jj = j + sub;
      int sn = __shfl(sn_l, jj, 64);
      if (jj < rem) {
        union { float4 f4; __half2 h2[4]; } u;
        u.f4 = *(const float4*)&ft[(size_t)sn * F + ll * 8];
#pragma unroll
        for (int q = 0; q < 4; q++) hacc[q] = __hadd2(hacc[q], u.h2[q]);
      }
    }
  }

  // combine the EW edge streams (packed shfl over 'sub' lane bits)
#pragma unroll
  for (int o = 32; o >= LPR; o >>= 1) {
#pragma unroll
    for (int q = 0; q < 4; q++) {
      union { __half2 h; int i; } a, s;
      a.h = hacc[q];
      s.i = __shfl_xor(a.i, o, 64);
      hacc[q] = __hadd2(a.h, s.h);
    }
  }

  float acc[8];
#pragma unroll
  for (int q = 0; q < 4; q++) {
    float2 f = __half22float2(hacc[q]);
    acc[2 * q + 0] = f.x;
    acc[2 * q + 1] = f.y;
  }

  float sc = (deg > 0) ? (1.0f / (float)deg) : 0.f;
  float4 b4a = *(const float4*)&bias[ll * 8 + 0];
  float4 b4b = *(const float4*)&bias[ll * 8 + 4];
  acc[0] = fmaf(acc[0], sc, b4a.x); acc[1] = fmaf(acc[1], sc, b4a.y);
  acc[2] = fmaf(acc[2], sc, b4a.z); acc[3] = fmaf(acc[3], sc, b4a.w);
  acc[4] = fmaf(acc[4], sc, b4b.x); acc[5] = fmaf(acc[5], sc, b4b.y);
  acc[6] = fmaf(acc[6], sc, b4b.z); acc[7] = fmaf(acc[7], sc, b4b.w);

  if (LN) {
    float sum = 0.f;
#pragma unroll
    for (int q = 0; q < 8; q++) sum += acc[q];
#pragma unroll
    for (int o = LPR / 2; o > 0; o >>= 1) sum += __shfl_xor(sum, o, 64);
    float mean = sum * (1.0f / 128.0f);
    float var = 0.f;
#pragma unroll
    for (int q = 0; q < 8; q++) { acc[q] -= mean; var = fmaf(acc[q], acc[q], var); }
#pragma unroll
    for (int o = LPR / 2; o > 0; o >>= 1) var += __shfl_xor(var, o, 64);
    float r = rsqrtf(var * (1.0f / 128.0f) + 1e-5f);
    float4 g4a = *(const float4*)&g[ll * 8 + 0];
    float4 g4b = *(const float4*)&g[ll * 8 + 4];
    float4 be4a = *(const float4*)&beta[ll * 8 + 0];
    float4 be4b = *(const float4*)&beta[ll * 8 + 4];
    acc[0] = fmaxf(acc[0] * r * g4a.x + be4a.x, 0.f);
    acc[1] = fmaxf(acc[1] * r * g4a.y + be4a.y, 0.f);
    acc[2] = fmaxf(acc[2] * r * g4a.z + be4a.z, 0.f);
    acc[3] = fmaxf(acc[3] * r * g4a.w + be4a.w, 0.f);
    acc[4] = fmaxf(acc[4] * r * g4b.x + be4b.x, 0.f);
    acc[5] = fmaxf(acc[5] * r * g4b.y + be4b.y, 0.f);
    acc[6] = fmaxf(acc[6] * r * g4b.z + be4b.z, 0.f);
    acc[7] = fmaxf(acc[7] * r * g4b.w + be4b.w, 0.f);
  }
  if (sub == 0) {
    if (HOUT) {
      __half* outh = (__half*)out_v;
      union { __half2 h2[4]; int4 i4; } u;
      u.h2[0] = __floats2half2_rn(acc[0], acc[1]);
      u.h2[1] = __floats2half2_rn(acc[2], acc[3]);
      u.h2[2] = __floats2half2_rn(acc[4], acc[5]);
      u.h2[3] = __floats2half2_rn(acc[6], acc[7]);
      *(int4*)&outh[(size_t)gw * F + ll * 8] = u.i4;
    } else {
      float* outf = (float*)out_v;
      *(float4*)&outf[(size_t)gw * F + ll * 8 + 0] = make_float4(acc[0], acc[1], acc[2], acc[3]);
      *(float4*)&outf[(size_t)gw * F + ll * 8 + 4] = make_float4(acc[4], acc[5], acc[6], acc[7]);
    }
  }
}

// ---------------- CSR build v4: 2 kernels ----------------
// stage: single pass over edges. LDS per-bucket count -> reserve offset-within-bucket via
// one global atomic per (block,bucket) on zero-initialized bhist -> scatter into fixed
// BCAP-slot bucket regions. After all blocks: bhist[b*CPAD] = bucket total.
__global__ __launch_bounds__(256) void stage_kernel(const int* __restrict__ src,
                                                    const int* __restrict__ dst,
                                                    int* __restrict__ bhist,
                                                    int* __restrict__ staged) {
  __shared__ int cnt[256];
  __shared__ int basep[256];
  __shared__ int cur[256];
  int tid = threadIdx.x;
  cnt[tid] = 0;
  cur[tid] = 0;
  __syncthreads();
#pragma unroll
  for (int q = 0; q < 4; q++) {
    int base = blockIdx.x * STILE + q * 1024 + tid * 4;
    if (base + 3 < NE) {
      int4 d = *(const int4*)&dst[base];
      atomicAdd(&cnt[d.x >> 8], 1);
      atomicAdd(&cnt[d.y >> 8], 1);
      atomicAdd(&cnt[d.z >> 8], 1);
      atomicAdd(&cnt[d.w >> 8], 1);
    } else {
#pragma unroll
      for (int k = 0; k < 4; k++)
        if (base + k < NE) atomicAdd(&cnt[dst[base + k] >> 8], 1);
    }
  }
  __syncthreads();
  if (tid < NB) basep[tid] = (cnt[tid] > 0) ? atomicAdd(&bhist[tid * CPAD], cnt[tid]) : 0;
  __syncthreads();
#pragma unroll
  for (int q = 0; q < 4; q++) {
    int base = blockIdx.x * STILE + q * 1024 + tid * 4;
    if (base + 3 < NE) {
      int4 d = *(const int4*)&dst[base];
      int4 s = *(const int4*)&src[base];
      int b0 = d.x >> 8, b1 = d.y >> 8, b2 = d.z >> 8, b3 = d.w >> 8;
      int p0 = atomicAdd(&cur[b0], 1);
      staged[b0 * BCAP + basep[b0] + p0] = s.x | ((d.x & 255) << 16);
      int p1 = atomicAdd(&cur[b1], 1);
      staged[b1 * BCAP + basep[b1] + p1] = s.y | ((d.y & 255) << 16);
      int p2 = atomicAdd(&cur[b2], 1);
      staged[b2 * BCAP + basep[b2] + p2] = s.z | ((d.z & 255) << 16);
      int p3 = atomicAdd(&cur[b3], 1);
      staged[b3 * BCAP + basep[b3] + p3] = s.w | ((d.w & 255) << 16);
    } else {
#pragma unroll
      for (int k = 0; k < 4; k++) {
        if (base + k < NE) {
          int d = dst[base + k], s = src[base + k];
          int bb = d >> 8;
          int pp = atomicAdd(&cur[bb], 1);
          staged[bb * BCAP + basep[bb] + pp] = s | ((d & 255) << 16);
        }
      }
    }
  }
}

// bucket_csr: one block per bucket. In-block exclusive scan of the 196 bucket totals gives
// this bucket's global es base (replaces the bscan kernel), then LDS per-dst hist + scan ->
// row_ptr + es.
__global__ __launch_bounds__(256) void bucket_csr_kernel(const int* __restrict__ staged,
                                                         const int* __restrict__ bhist,
                                                         int* __restrict__ row_ptr,
                                                         unsigned short* __restrict__ es) {
  int b = blockIdx.x;
  int tid = threadIdx.x;
  int lane = tid & 63, wid = tid >> 6;
  __shared__ int sbase[256];
  __shared__ int wsum[4];
  __shared__ int cnt[256];
  __shared__ int fill_l[256];
  // exclusive scan of bucket totals -> global es base for this bucket
  int tv = (tid < NB) ? bhist[tid * CPAD] : 0;
  int x = tv;
#pragma unroll
  for (int o = 1; o < 64; o <<= 1) {
    int y = __shfl_up(x, o, 64);
    if (lane >= o) x += y;
  }
  if (lane == 63) wsum[wid] = x;
  __syncthreads();
  int wpre = 0;
  for (int w = 0; w < wid; w++) wpre += wsum[w];
  sbase[tid] = wpre + x - tv;
  cnt[tid] = 0;
  __syncthreads();
  int lo = sbase[b];                 // global es offset of this bucket
  int cntb = bhist[b * CPAD];        // edges in this bucket
  const int* st = &staged[b * BCAP];
  for (int i = tid; i < cntb; i += 256)
    atomicAdd(&cnt[(st[i] >> 16) & 255], 1);
  __syncthreads();
  int v = cnt[tid];
  x = v;
#pragma unroll
  for (int o = 1; o < 64; o <<= 1) {
    int y = __shfl_up(x, o, 64);
    if (lane >= o) x += y;
  }
  __syncthreads();                    // wsum reuse
  if (lane == 63) wsum[wid] = x;
  __syncthreads();
  wpre = 0;
  for (int w = 0; w < wid; w++) wpre += wsum[w];
  int start = lo + wpre + x - v;      // absolute exclusive prefix
  int node = (b << 8) + tid;
  if (node < NN) row_ptr[node] = start;
  fill_l[tid] = start;
  __syncthreads();
  for (int i = tid; i < cntb; i += 256) {
    int w = st[i];
    int pos = atomicAdd(&fill_l[(w >> 16) & 255], 1);
    es[pos] = (unsigned short)(w & 0xFFFF);
  }
  if (b == 0 && tid == 0) row_ptr[NN] = NE;
}

// ---------------- orchestration ----------------
extern "C" void kernel_launch(void* const* d_in, const int* in_sizes, int n_in,
                              void* d_out, int out_size, void* d_ws, size_t ws_size,
                              hipStream_t stream) {
  (void)in_sizes; (void)n_in; (void)out_size; (void)ws_size;
  const float* feat = (const float*)d_in[0];
  const int* src = (const int*)d_in[1];
  const int* dst = (const int*)d_in[2];
  const float* W0 = (const float*)d_in[3];
  const float* b0 = (const float*)d_in[4];
  const float* W1 = (const float*)d_in[5];
  const float* b1 = (const float*)d_in[6];
  const float* W2 = (const float*)d_in[7];
  const float* b2 = (const float*)d_in[8];
  const float* ln1g = (const float*)d_in[9];
  const float* ln1b = (const float*)d_in[10];
  const float* ln2g = (const float*)d_in[11];
  const float* ln2b = (const float*)d_in[12];
  float* out = (float*)d_out;

  char* p = (char*)d_ws;
  auto alloc = [&](size_t bytes) {
    char* r = p;
    p += (bytes + 255) & ~size_t(255);
    return r;
  };
  __half* fth      = (__half*)alloc((size_t)NN * 128 * 2);
  __half* hh       = (__half*)alloc((size_t)NN * 128 * 2);
  __half* W0T      = (__half*)alloc(128 * 128 * 2);
  __half* W1T      = (__half*)alloc(128 * 128 * 2);
  __half* W2T      = (__half*)alloc(64 * 128 * 2);
  int* row_ptr     = (int*)alloc((size_t)(NN + 1) * 4);
  unsigned short* es = (unsigned short*)alloc((size_t)NE * 2);
  int* staged      = (int*)alloc((size_t)NB * BCAP * 4);
  int* bhist       = (int*)alloc((size_t)NB * CPAD * 4);

  // convert weights + zero bhist
  convert_kernel<<<160, 256, 0, stream>>>(W0, W1, W2, W0T, W1T, W2T, bhist);

  // CSR by dst (graph identical for all 3 convs): 2 kernels
  int sb = (NE + STILE - 1) / STILE;   // 196 blocks
  stage_kernel<<<sb, 256, 0, stream>>>(src, dst, bhist, staged);
  bucket_csr_kernel<<<NB, 256, 0, stream>>>(staged, bhist, row_ptr, es);

  int gb = (NN + 63) / 64;     // 782
  int nwb = (NN + 3) / 4;

  gemm_mfma<128, true><<<gb, 256, 0, stream>>>(feat, W0T, fth, NN);
  agg_kernel<128, true, true><<<nwb, 256, 0, stream>>>(fth, row_ptr, es, b0, ln1g, ln1b, hh, NN);
  gemm_mfma<128, false><<<gb, 256, 0, stream>>>(hh, W1T, fth, NN);
  agg_kernel<128, true, true><<<nwb, 256, 0, stream>>>(fth, row_ptr, es, b1, ln2g, ln2b, hh, NN);
  gemm_mfma<64, false><<<gb, 256, 0, stream>>>(hh, W2T, fth, NN);
  agg_kernel<64, false, false><<<nwb, 256, 0, stream>>>(fth, row_ptr, es, b2, nullptr, nullptr, out, NN);
}